// Round 1
// baseline (426.728 us; speedup 1.0000x reference)
//
#include <hip/hip_runtime.h>
#include <hip/hip_bf16.h>

typedef __bf16 bf16x8_t __attribute__((ext_vector_type(8)));
typedef __bf16 bf16x4_t __attribute__((ext_vector_type(4)));
typedef float f32x4_t __attribute__((ext_vector_type(4)));

__device__ __forceinline__ void gload_lds16(const void* g, void* l) {
    __builtin_amdgcn_global_load_lds((const __attribute__((address_space(1))) void*)g,
                                     (__attribute__((address_space(3))) void*)l, 16, 0, 0);
}

// ---------------- fp32 -> bf16 conversion ----------------
__global__ void f2bf_kernel(const float* __restrict__ in, __bf16* __restrict__ out, int n) {
    int i = (blockIdx.x * blockDim.x + threadIdx.x) * 4;
    if (i >= n) return;
    float4 v = *(const float4*)(in + i);
    bf16x4_t o;
    o[0] = (__bf16)v.x; o[1] = (__bf16)v.y; o[2] = (__bf16)v.z; o[3] = (__bf16)v.w;
    *(bf16x4_t*)(out + i) = o;
}

// ---------------- bf16 GEMM: C[M,N] = A[M,K] * Bt[N,K]^T ----------------
// 128x128 tile, BK=32, 4 waves (2x2), each wave 64x64 via 4x4 16x16x32 mfma.
template <typename OutT>
__global__ __launch_bounds__(256) void gemm_bt(const __bf16* __restrict__ A,
                                               const __bf16* __restrict__ Bt,
                                               OutT* __restrict__ C,
                                               int M, int N, int K) {
    __shared__ __bf16 As[128 * 32];
    __shared__ __bf16 Bs[128 * 32];

    const int tid  = threadIdx.x;
    const int lane = tid & 63;
    const int wid  = tid >> 6;
    const int wm   = wid >> 1;   // 0..1
    const int wn   = wid & 1;    // 0..1
    const int m0   = blockIdx.y * 128;
    const int n0   = blockIdx.x * 128;

    const int lr = lane & 15;          // frag row/col
    const int lk = (lane >> 4) * 8;    // frag k offset
    const int cr = (lane >> 4) * 4;    // C row base

    f32x4_t acc[4][4];
    for (int i = 0; i < 4; ++i)
        for (int j = 0; j < 4; ++j)
            acc[i][j] = (f32x4_t){0.f, 0.f, 0.f, 0.f};

    for (int k0 = 0; k0 < K; k0 += 32) {
        __syncthreads();
        // stage A,B tiles: each pass = 256 threads * 16B = half a tile
        for (int i = 0; i < 2; ++i) {
            int flat = i * 256 + tid;        // 8-bf16 chunk id
            int row  = flat >> 2;            // /4 chunks per row
            int col  = (flat & 3) * 8;
            gload_lds16(&A[(size_t)(m0 + row) * K + k0 + col], &As[(size_t)(i * 256 + wid * 64) * 8]);
            gload_lds16(&Bt[(size_t)(n0 + row) * K + k0 + col], &Bs[(size_t)(i * 256 + wid * 64) * 8]);
        }
        __syncthreads();

        bf16x8_t af[4], bfr[4];
        for (int mf = 0; mf < 4; ++mf)
            af[mf] = *(const bf16x8_t*)&As[(wm * 64 + mf * 16 + lr) * 32 + lk];
        for (int nf = 0; nf < 4; ++nf)
            bfr[nf] = *(const bf16x8_t*)&Bs[(wn * 64 + nf * 16 + lr) * 32 + lk];
        for (int mf = 0; mf < 4; ++mf)
            for (int nf = 0; nf < 4; ++nf)
                acc[mf][nf] = __builtin_amdgcn_mfma_f32_16x16x32_bf16(af[mf], bfr[nf], acc[mf][nf], 0, 0, 0);
    }

    for (int mf = 0; mf < 4; ++mf)
        for (int nf = 0; nf < 4; ++nf)
            for (int r = 0; r < 4; ++r) {
                int row = m0 + wm * 64 + mf * 16 + cr + r;
                int col = n0 + wn * 64 + nf * 16 + lr;
                C[(size_t)row * N + col] = (OutT)acc[mf][nf][r];
            }
}

// ---------------- flash attention (causal) ----------------
// qkv: [B*T, 3C] bf16 row-major. y: [B*T, C] bf16.
// block = 256 threads (4 waves); block handles one (b, h, 64-row q-tile);
// each wave owns 16 q-rows. K/V staged in 64-key LDS tiles (stride 72 to
// avoid bank conflicts), V stored transposed [dim][key].
__global__ __launch_bounds__(256) void attn_kernel(const __bf16* __restrict__ qkv,
                                                   __bf16* __restrict__ y) {
    const int T = 2048, C3 = 3072, HD = 64;
    const int bidx = blockIdx.x;
    const int qt   = bidx & 31;           // T/64 = 32 q-tiles
    const int h    = (bidx >> 5) & 15;
    const int b    = bidx >> 9;
    const int qt0  = qt * 64;

    __shared__ __bf16 Qs[64 * 72];
    __shared__ __bf16 Ks[64 * 72];
    __shared__ __bf16 Vt[64 * 72];   // [dim][key]
    __shared__ __bf16 Ps[64 * 72];   // per-wave 16-row P staging

    const int tid  = threadIdx.x;
    const int lane = tid & 63;
    const int w    = tid >> 6;
    const int lr   = lane & 15;
    const int lg   = lane >> 4;
    const int lk   = lg * 8;
    const int cr   = lg * 4;

    const __bf16* qg = qkv + (size_t)(b * T + qt0) * C3 + h * HD;
    const __bf16* kg = qkv + (size_t)b * T * C3 + 1024 + h * HD;
    const __bf16* vg = qkv + (size_t)b * T * C3 + 2048 + h * HD;

    // load Q tile [64][64]
    for (int i = tid; i < 512; i += 256) {
        int r = i >> 3, c = (i & 7) * 8;
        *(bf16x8_t*)&Qs[r * 72 + c] = *(const bf16x8_t*)&qg[(size_t)r * C3 + c];
    }
    __syncthreads();
    bf16x8_t qf[2];
    qf[0] = *(const bf16x8_t*)&Qs[(w * 16 + lr) * 72 + 0 + lk];
    qf[1] = *(const bf16x8_t*)&Qs[(w * 16 + lr) * 72 + 32 + lk];

    f32x4_t o_acc[4];
    for (int i = 0; i < 4; ++i) o_acc[i] = (f32x4_t){0.f, 0.f, 0.f, 0.f};
    float m_r[4] = {-1e30f, -1e30f, -1e30f, -1e30f};
    float l_r[4] = {0.f, 0.f, 0.f, 0.f};

    const float scale = 0.125f;  // 1/sqrt(64)

    for (int kt0 = 0; kt0 <= qt0; kt0 += 64) {
        __syncthreads();
        for (int i = tid; i < 512; i += 256) {
            int r = i >> 3, c = (i & 7) * 8;
            *(bf16x8_t*)&Ks[r * 72 + c] = *(const bf16x8_t*)&kg[(size_t)(kt0 + r) * C3 + c];
            bf16x8_t vv = *(const bf16x8_t*)&vg[(size_t)(kt0 + r) * C3 + c];
            for (int j = 0; j < 8; ++j) Vt[(c + j) * 72 + r] = vv[j];
        }
        __syncthreads();

        // S = Q K^T  (wave's 16 q-rows x 64 keys)
        f32x4_t s[4];
        for (int c = 0; c < 4; ++c) {
            s[c] = (f32x4_t){0.f, 0.f, 0.f, 0.f};
            for (int kk = 0; kk < 2; ++kk) {
                bf16x8_t kf = *(const bf16x8_t*)&Ks[(c * 16 + lr) * 72 + kk * 32 + lk];
                s[c] = __builtin_amdgcn_mfma_f32_16x16x32_bf16(qf[kk], kf, s[c], 0, 0, 0);
            }
        }

        // scale + causal mask + row max
        float pm[4] = {-1e30f, -1e30f, -1e30f, -1e30f};
        for (int c = 0; c < 4; ++c) {
            int kcol = kt0 + c * 16 + lr;
            for (int r = 0; r < 4; ++r) {
                int qrow = qt0 + w * 16 + cr + r;
                float sv = s[c][r] * scale;
                if (kcol > qrow) sv = -1e30f;
                s[c][r] = sv;
                pm[r] = fmaxf(pm[r], sv);
            }
        }
        for (int off = 8; off >= 1; off >>= 1)
            for (int r = 0; r < 4; ++r)
                pm[r] = fmaxf(pm[r], __shfl_xor(pm[r], off));

        float alpha[4], rs[4];
        for (int r = 0; r < 4; ++r) {
            float mn = fmaxf(m_r[r], pm[r]);
            alpha[r] = __expf(m_r[r] - mn);
            m_r[r] = mn;
            rs[r] = 0.f;
        }
        for (int c = 0; c < 4; ++c)
            for (int r = 0; r < 4; ++r) {
                float pv = __expf(s[c][r] - m_r[r]);
                s[c][r] = pv;
                rs[r] += pv;
            }
        for (int off = 8; off >= 1; off >>= 1)
            for (int r = 0; r < 4; ++r)
                rs[r] += __shfl_xor(rs[r], off);
        for (int r = 0; r < 4; ++r) l_r[r] = l_r[r] * alpha[r] + rs[r];
        for (int dt = 0; dt < 4; ++dt)
            for (int r = 0; r < 4; ++r)
                o_acc[dt][r] *= alpha[r];

        // P -> LDS (bf16), transposing from C-layout to A-operand layout
        __bf16* Pw = &Ps[w * 16 * 72];
        for (int c = 0; c < 4; ++c)
            for (int r = 0; r < 4; ++r)
                Pw[(cr + r) * 72 + c * 16 + lr] = (__bf16)s[c][r];

        bf16x8_t pa[2];
        pa[0] = *(const bf16x8_t*)&Pw[lr * 72 + 0 + lk];
        pa[1] = *(const bf16x8_t*)&Pw[lr * 72 + 32 + lk];
        for (int dt = 0; dt < 4; ++dt)
            for (int kk = 0; kk < 2; ++kk) {
                bf16x8_t vb = *(const bf16x8_t*)&Vt[(dt * 16 + lr) * 72 + kk * 32 + lk];
                o_acc[dt] = __builtin_amdgcn_mfma_f32_16x16x32_bf16(pa[kk], vb, o_acc[dt], 0, 0, 0);
            }
    }

    for (int dt = 0; dt < 4; ++dt)
        for (int r = 0; r < 4; ++r) {
            int q = qt0 + w * 16 + cr + r;
            int d = dt * 16 + lr;
            y[(size_t)(b * T + q) * 1024 + h * HD + d] = (__bf16)(o_acc[dt][r] / l_r[r]);
        }
}

// ---------------- launch ----------------
extern "C" void kernel_launch(void* const* d_in, const int* in_sizes, int n_in,
                              void* d_out, int out_size, void* d_ws, size_t ws_size,
                              hipStream_t stream) {
    const float* x      = (const float*)d_in[0];
    const float* w_attn = (const float*)d_in[1];
    const float* w_proj = (const float*)d_in[2];
    float* out = (float*)d_out;

    char* ws = (char*)d_ws;
    __bf16* xb   = (__bf16*)(ws);                      // 8192*1024   = 16 MB
    __bf16* wab  = (__bf16*)(ws + 16777216);           // 3072*1024   = 6 MB
    __bf16* wpb  = (__bf16*)(ws + 23068672);           // 1024*1024   = 2 MB
    __bf16* qkvb = (__bf16*)(ws + 25165824);           // 8192*3072   = 48 MB
    __bf16* yb   = (__bf16*)(ws + 75497472);           // 8192*1024   = 16 MB

    f2bf_kernel<<<8192, 256, 0, stream>>>(x, xb, 8388608);
    f2bf_kernel<<<3072, 256, 0, stream>>>(w_attn, wab, 3145728);
    f2bf_kernel<<<1024, 256, 0, stream>>>(w_proj, wpb, 1048576);

    // qkv = x @ w_attn^T   [8192, 3072]
    gemm_bt<__bf16><<<dim3(24, 64), 256, 0, stream>>>(xb, wab, qkvb, 8192, 3072, 1024);

    // flash attention -> yb [8192, 1024]
    attn_kernel<<<2048, 256, 0, stream>>>(qkvb, yb);

    // out = yb @ w_proj^T  [8192, 1024] fp32
    gemm_bt<float><<<dim3(8, 64), 256, 0, stream>>>(yb, wpb, out, 8192, 1024, 1024);
}

// Round 2
// 269.365 us; speedup vs baseline: 1.5842x; 1.5842x over previous
//
#include <hip/hip_runtime.h>
#include <hip/hip_bf16.h>

typedef __bf16 bf16x8_t __attribute__((ext_vector_type(8)));
typedef __bf16 bf16x4_t __attribute__((ext_vector_type(4)));
typedef float f32x4_t __attribute__((ext_vector_type(4)));

__device__ __forceinline__ void gload_lds16(const void* g, void* l) {
    __builtin_amdgcn_global_load_lds((const __attribute__((address_space(1))) void*)g,
                                     (__attribute__((address_space(3))) void*)l, 16, 0, 0);
}

// ---------------- fp32 -> bf16 conversion ----------------
__global__ void f2bf_kernel(const float* __restrict__ in, __bf16* __restrict__ out, int n) {
    int i = (blockIdx.x * blockDim.x + threadIdx.x) * 4;
    if (i >= n) return;
    float4 v = *(const float4*)(in + i);
    bf16x4_t o;
    o[0] = (__bf16)v.x; o[1] = (__bf16)v.y; o[2] = (__bf16)v.z; o[3] = (__bf16)v.w;
    *(bf16x4_t*)(out + i) = o;
}

// ---------------- bf16 GEMM: C[M,N] = A[M,K] * Bt[N,K]^T ----------------
template <typename OutT>
__global__ __launch_bounds__(256) void gemm_bt(const __bf16* __restrict__ A,
                                               const __bf16* __restrict__ Bt,
                                               OutT* __restrict__ C,
                                               int M, int N, int K) {
    __shared__ __bf16 As[128 * 32];
    __shared__ __bf16 Bs[128 * 32];

    const int tid  = threadIdx.x;
    const int lane = tid & 63;
    const int wid  = tid >> 6;
    const int wm   = wid >> 1;
    const int wn   = wid & 1;
    const int m0   = blockIdx.y * 128;
    const int n0   = blockIdx.x * 128;

    const int lr = lane & 15;
    const int lk = (lane >> 4) * 8;
    const int cr = (lane >> 4) * 4;

    f32x4_t acc[4][4];
    for (int i = 0; i < 4; ++i)
        for (int j = 0; j < 4; ++j)
            acc[i][j] = (f32x4_t){0.f, 0.f, 0.f, 0.f};

    for (int k0 = 0; k0 < K; k0 += 32) {
        __syncthreads();
        for (int i = 0; i < 2; ++i) {
            int flat = i * 256 + tid;
            int row  = flat >> 2;
            int col  = (flat & 3) * 8;
            gload_lds16(&A[(size_t)(m0 + row) * K + k0 + col], &As[(size_t)(i * 256 + wid * 64) * 8]);
            gload_lds16(&Bt[(size_t)(n0 + row) * K + k0 + col], &Bs[(size_t)(i * 256 + wid * 64) * 8]);
        }
        __syncthreads();

        bf16x8_t af[4], bfr[4];
        for (int mf = 0; mf < 4; ++mf)
            af[mf] = *(const bf16x8_t*)&As[(wm * 64 + mf * 16 + lr) * 32 + lk];
        for (int nf = 0; nf < 4; ++nf)
            bfr[nf] = *(const bf16x8_t*)&Bs[(wn * 64 + nf * 16 + lr) * 32 + lk];
        for (int mf = 0; mf < 4; ++mf)
            for (int nf = 0; nf < 4; ++nf)
                acc[mf][nf] = __builtin_amdgcn_mfma_f32_16x16x32_bf16(af[mf], bfr[nf], acc[mf][nf], 0, 0, 0);
    }

    for (int mf = 0; mf < 4; ++mf)
        for (int nf = 0; nf < 4; ++nf)
            for (int r = 0; r < 4; ++r) {
                int row = m0 + wm * 64 + mf * 16 + cr + r;
                int col = n0 + wn * 64 + nf * 16 + lr;
                C[(size_t)row * N + col] = (OutT)acc[mf][nf][r];
            }
}

// ---------------- flash attention (causal), v2 ----------------
// 1024 blocks = B(4) x H(16) x pair(16). Each block does q-tiles p and 31-p
// => exactly 33 k-tile iterations (work-balanced, all blocks resident).
// K staged via global_load_lds with pre-swizzled source (slot = kdim ^ ((key&7)*8)).
// V staged reg->LDS transposed [d][key] with key ^= ((d>>3)&7)*8 swizzle.
__global__ __launch_bounds__(256) void attn_kernel(const __bf16* __restrict__ qkv,
                                                   __bf16* __restrict__ y) {
    const int T = 2048, C3 = 3072, HD = 64;
    const int bidx = blockIdx.x;
    const int pair = bidx & 15;
    const int h    = (bidx >> 4) & 15;
    const int b    = bidx >> 8;

    __shared__ __bf16 Ks[64 * 64];   // linear, content swizzled within rows
    __shared__ __bf16 Vt[64 * 72];   // [d][key], key swizzled
    __shared__ __bf16 Ps[64 * 72];   // per-wave 16-row P staging

    const int tid  = threadIdx.x;
    const int lane = tid & 63;
    const int w    = tid >> 6;
    const int lr   = lane & 15;
    const int lg   = lane >> 4;
    const int lk   = lg * 8;
    const int cr   = lg * 4;

    const __bf16* qg = qkv + (size_t)b * T * C3 + h * HD;
    const __bf16* kg = qkv + (size_t)b * T * C3 + 1024 + h * HD;
    const __bf16* vg = qkv + (size_t)b * T * C3 + 2048 + h * HD;

    const float CE = 0.125f * 1.44269504f;  // scale * log2(e)

    for (int pass = 0; pass < 2; ++pass) {
        const int qt  = pass == 0 ? pair : 31 - pair;
        const int qt0 = qt * 64;

        // Q fragments straight from global (A-frag is contiguous 16B per lane)
        bf16x8_t qf[2];
        {
            const __bf16* qrow = qg + (size_t)(qt0 + w * 16 + lr) * C3;
            qf[0] = *(const bf16x8_t*)&qrow[0 + lk];
            qf[1] = *(const bf16x8_t*)&qrow[32 + lk];
        }

        f32x4_t o_acc[4];
        for (int i = 0; i < 4; ++i) o_acc[i] = (f32x4_t){0.f, 0.f, 0.f, 0.f};
        float m_r[4] = {-3.0e38f, -3.0e38f, -3.0e38f, -3.0e38f};
        float l_r[4] = {0.f, 0.f, 0.f, 0.f};

        for (int kt0 = 0; kt0 <= qt0; kt0 += 64) {
            __syncthreads();   // previous tile's compute done reading LDS

            // --- stage K: 2 x global_load_lds(16B) per wave, pre-swizzled src ---
            {
                int rb0 = w * 8;
                int rb1 = 32 + w * 8;
                int keyo = lane >> 3;                       // 0..7 within 8-row group
                int slot = (((lane & 7) ^ keyo) << 3);      // pre-swizzled kdim base
                gload_lds16(&kg[(size_t)(kt0 + rb0 + keyo) * C3 + slot], &Ks[rb0 * 64]);
                gload_lds16(&kg[(size_t)(kt0 + rb1 + keyo) * C3 + slot], &Ks[rb1 * 64]);
            }
            // --- stage V transposed with swizzle ---
            for (int ii = 0; ii < 2; ++ii) {
                int i = ii * 256 + tid;
                int r     = i >> 3;            // key 0..63
                int cbase = (i & 7) * 8;       // dim base
                bf16x8_t vv = *(const bf16x8_t*)&vg[(size_t)(kt0 + r) * C3 + cbase];
                int ks = r ^ ((((unsigned)cbase >> 3) & 7) << 3);  // swizzled key slot
                for (int j = 0; j < 8; ++j)
                    Vt[(cbase + j) * 72 + ks] = vv[j];
            }
            __syncthreads();

            // --- S = Q K^T (16 q-rows x 64 keys per wave) ---
            f32x4_t s[4];
            for (int c = 0; c < 4; ++c) {
                s[c] = (f32x4_t){0.f, 0.f, 0.f, 0.f};
                int key = c * 16 + lr;
                int sw  = (key & 7) << 3;
                for (int kk = 0; kk < 2; ++kk) {
                    bf16x8_t kf = *(const bf16x8_t*)&Ks[key * 64 + ((kk * 32 + lk) ^ sw)];
                    s[c] = __builtin_amdgcn_mfma_f32_16x16x32_bf16(qf[kk], kf, s[c], 0, 0, 0);
                }
            }

            // --- causal mask: only the diagonal tile needs it ---
            if (kt0 == qt0) {
                for (int c = 0; c < 4; ++c) {
                    int kcol = c * 16 + lr;
                    for (int r = 0; r < 4; ++r) {
                        int qrow = w * 16 + cr + r;
                        if (kcol > qrow) s[c][r] = -1.0e30f;
                    }
                }
            }

            // --- online softmax (raw-domain max, exp2 with folded scale) ---
            float pm[4] = {-3.0e38f, -3.0e38f, -3.0e38f, -3.0e38f};
            for (int c = 0; c < 4; ++c)
                for (int r = 0; r < 4; ++r)
                    pm[r] = fmaxf(pm[r], s[c][r]);
            for (int off = 8; off >= 1; off >>= 1)
                for (int r = 0; r < 4; ++r)
                    pm[r] = fmaxf(pm[r], __shfl_xor(pm[r], off));

            float alpha[4], mce[4], rs[4];
            for (int r = 0; r < 4; ++r) {
                float mn = fmaxf(m_r[r], pm[r]);
                alpha[r] = exp2f((m_r[r] - mn) * CE);
                m_r[r]   = mn;
                mce[r]   = mn * CE;
                rs[r]    = 0.f;
            }
            for (int c = 0; c < 4; ++c)
                for (int r = 0; r < 4; ++r) {
                    float pv = exp2f(fmaf(s[c][r], CE, -mce[r]));
                    s[c][r] = pv;
                    rs[r] += pv;
                }
            for (int off = 8; off >= 1; off >>= 1)
                for (int r = 0; r < 4; ++r)
                    rs[r] += __shfl_xor(rs[r], off);
            for (int r = 0; r < 4; ++r) l_r[r] = l_r[r] * alpha[r] + rs[r];
            for (int dt = 0; dt < 4; ++dt)
                for (int r = 0; r < 4; ++r)
                    o_acc[dt][r] *= alpha[r];

            // --- P -> LDS (transpose C-layout -> A-operand layout) ---
            __bf16* Pw = &Ps[w * 16 * 72];
            for (int c = 0; c < 4; ++c)
                for (int r = 0; r < 4; ++r)
                    Pw[(cr + r) * 72 + c * 16 + lr] = (__bf16)s[c][r];

            bf16x8_t pa[2];
            pa[0] = *(const bf16x8_t*)&Pw[lr * 72 + 0 + lk];
            pa[1] = *(const bf16x8_t*)&Pw[lr * 72 + 32 + lk];
            for (int dt = 0; dt < 4; ++dt) {
                int d  = dt * 16 + lr;
                int sw = ((d >> 3) & 7) << 3;
                for (int kk = 0; kk < 2; ++kk) {
                    bf16x8_t vb = *(const bf16x8_t*)&Vt[d * 72 + ((kk * 32 + lk) ^ sw)];
                    o_acc[dt] = __builtin_amdgcn_mfma_f32_16x16x32_bf16(pa[kk], vb, o_acc[dt], 0, 0, 0);
                }
            }
        }

        for (int dt = 0; dt < 4; ++dt)
            for (int r = 0; r < 4; ++r) {
                int q = qt0 + w * 16 + cr + r;
                int d = dt * 16 + lr;
                y[(size_t)(b * T + q) * 1024 + h * HD + d] = (__bf16)(o_acc[dt][r] / l_r[r]);
            }
    }
}

// ---------------- launch ----------------
extern "C" void kernel_launch(void* const* d_in, const int* in_sizes, int n_in,
                              void* d_out, int out_size, void* d_ws, size_t ws_size,
                              hipStream_t stream) {
    const float* x      = (const float*)d_in[0];
    const float* w_attn = (const float*)d_in[1];
    const float* w_proj = (const float*)d_in[2];
    float* out = (float*)d_out;

    char* ws = (char*)d_ws;
    __bf16* xb   = (__bf16*)(ws);                      // 8192*1024   = 16 MB
    __bf16* wab  = (__bf16*)(ws + 16777216);           // 3072*1024   = 6 MB
    __bf16* wpb  = (__bf16*)(ws + 23068672);           // 1024*1024   = 2 MB
    __bf16* qkvb = (__bf16*)(ws + 25165824);           // 8192*3072   = 48 MB
    __bf16* yb   = (__bf16*)(ws + 75497472);           // 8192*1024   = 16 MB

    f2bf_kernel<<<8192, 256, 0, stream>>>(x, xb, 8388608);
    f2bf_kernel<<<3072, 256, 0, stream>>>(w_attn, wab, 3145728);
    f2bf_kernel<<<1024, 256, 0, stream>>>(w_proj, wpb, 1048576);

    // qkv = x @ w_attn^T   [8192, 3072]
    gemm_bt<__bf16><<<dim3(24, 64), 256, 0, stream>>>(xb, wab, qkvb, 8192, 3072, 1024);

    // flash attention -> yb [8192, 1024]
    attn_kernel<<<1024, 256, 0, stream>>>(qkvb, yb);

    // out = yb @ w_proj^T  [8192, 1024] fp32
    gemm_bt<float><<<dim3(8, 64), 256, 0, stream>>>(yb, wpb, out, 8192, 1024, 1024);
}

// Round 3
// 220.680 us; speedup vs baseline: 1.9337x; 1.2206x over previous
//
#include <hip/hip_runtime.h>
#include <hip/hip_bf16.h>

typedef __bf16 bf16x8_t __attribute__((ext_vector_type(8)));
typedef __bf16 bf16x4_t __attribute__((ext_vector_type(4)));
typedef float f32x4_t __attribute__((ext_vector_type(4)));

__device__ __forceinline__ void gload_lds16(const void* g, void* l) {
    __builtin_amdgcn_global_load_lds((const __attribute__((address_space(1))) void*)g,
                                     (__attribute__((address_space(3))) void*)l, 16, 0, 0);
}

// ---------------- fp32 -> bf16 conversion ----------------
__global__ void f2bf_kernel(const float* __restrict__ in, __bf16* __restrict__ out, int n) {
    int i = (blockIdx.x * blockDim.x + threadIdx.x) * 4;
    if (i >= n) return;
    float4 v = *(const float4*)(in + i);
    bf16x4_t o;
    o[0] = (__bf16)v.x; o[1] = (__bf16)v.y; o[2] = (__bf16)v.z; o[3] = (__bf16)v.w;
    *(bf16x4_t*)(out + i) = o;
}

// ---------------- bf16 GEMM: C[M,N] = A[M,K] * Bt[N,K]^T ----------------
template <typename OutT>
__global__ __launch_bounds__(256) void gemm_bt(const __bf16* __restrict__ A,
                                               const __bf16* __restrict__ Bt,
                                               OutT* __restrict__ C,
                                               int M, int N, int K) {
    __shared__ __bf16 As[128 * 32];
    __shared__ __bf16 Bs[128 * 32];

    const int tid  = threadIdx.x;
    const int lane = tid & 63;
    const int wid  = tid >> 6;
    const int wm   = wid >> 1;
    const int wn   = wid & 1;
    const int m0   = blockIdx.y * 128;
    const int n0   = blockIdx.x * 128;

    const int lr = lane & 15;
    const int lk = (lane >> 4) * 8;
    const int cr = (lane >> 4) * 4;

    f32x4_t acc[4][4];
    for (int i = 0; i < 4; ++i)
        for (int j = 0; j < 4; ++j)
            acc[i][j] = (f32x4_t){0.f, 0.f, 0.f, 0.f};

    for (int k0 = 0; k0 < K; k0 += 32) {
        __syncthreads();
        for (int i = 0; i < 2; ++i) {
            int flat = i * 256 + tid;
            int row  = flat >> 2;
            int col  = (flat & 3) * 8;
            gload_lds16(&A[(size_t)(m0 + row) * K + k0 + col], &As[(size_t)(i * 256 + wid * 64) * 8]);
            gload_lds16(&Bt[(size_t)(n0 + row) * K + k0 + col], &Bs[(size_t)(i * 256 + wid * 64) * 8]);
        }
        __syncthreads();

        bf16x8_t af[4], bfr[4];
        for (int mf = 0; mf < 4; ++mf)
            af[mf] = *(const bf16x8_t*)&As[(wm * 64 + mf * 16 + lr) * 32 + lk];
        for (int nf = 0; nf < 4; ++nf)
            bfr[nf] = *(const bf16x8_t*)&Bs[(wn * 64 + nf * 16 + lr) * 32 + lk];
        for (int mf = 0; mf < 4; ++mf)
            for (int nf = 0; nf < 4; ++nf)
                acc[mf][nf] = __builtin_amdgcn_mfma_f32_16x16x32_bf16(af[mf], bfr[nf], acc[mf][nf], 0, 0, 0);
    }

    for (int mf = 0; mf < 4; ++mf)
        for (int nf = 0; nf < 4; ++nf)
            for (int r = 0; r < 4; ++r) {
                int row = m0 + wm * 64 + mf * 16 + cr + r;
                int col = n0 + wn * 64 + nf * 16 + lr;
                C[(size_t)row * N + col] = (OutT)acc[mf][nf][r];
            }
}

// ---------------- flash attention (causal), v3: swapped-operand MFMA ----------------
// S^T = mfma(K,Q): lane holds 16 S values for ONE query (col=lane&15) ->
// softmax reduce is in-register + 2 shuffles; P staged as packed b64 rows
// Ps[q][key]; PV swapped (O^T = V^T P^T) so output stays query=lane&15.
// 1-deep pipeline: K(t+1) gload_lds + V(t+1) reg loads issued at start of
// compute(t); __syncthreads' forced vmcnt(0) then drains landed loads.
__global__ __launch_bounds__(256) void attn_kernel(const __bf16* __restrict__ qkv,
                                                   __bf16* __restrict__ y) {
    const int T = 2048, C3 = 3072, HD = 64;
    const int bidx = blockIdx.x;
    const int pair = bidx & 15;
    const int h    = (bidx >> 4) & 15;
    const int b    = bidx >> 8;

    __shared__ __bf16 Ks[2][64 * 64];  // dbuf, content pre-swizzled per row
    __shared__ __bf16 Vt[64 * 72];     // [d][key], key slot swizzled
    __shared__ __bf16 Ps[64 * 72];     // [q][key], per-wave 16-row slice

    const int tid  = threadIdx.x;
    const int lane = tid & 63;
    const int w    = tid >> 6;
    const int lr   = lane & 15;
    const int lg   = lane >> 4;
    const int lk   = lg * 8;

    const __bf16* qg = qkv + (size_t)b * T * C3 + h * HD;
    const __bf16* kg = qg + 1024;
    const __bf16* vg = qg + 2048;

    const float CE = 0.125f * 1.44269504f;  // scale * log2(e)

    // V-stage mapping: thread covers keys vr0, vr0+32 at dims vcb..vcb+7
    const int vr0 = tid >> 3;
    const int vcb = (tid & 7) * 8;
    const int vsw = ((vcb >> 3) & 7) << 3;
    const int ks0 = vr0 ^ vsw;
    const int ks1 = (vr0 + 32) ^ vsw;
    // K-stage mapping (global_load_lds, pre-swizzled source)
    const int krb0 = w * 8, krb1 = 32 + w * 8;
    const int keyo = lane >> 3;
    const int kslot = ((lane & 7) ^ keyo) << 3;

    __bf16* Pw = &Ps[(w * 16) * 72];

    for (int pass = 0; pass < 2; ++pass) {
        const int qt  = pass == 0 ? pair : 31 - pair;
        const int qt0 = qt * 64;
        const int nt  = qt + 1;

        __syncthreads();  // previous pass compute fully done: buffers free

        // prologue: stage K(0), load V(0) regs, load Q fragments
        gload_lds16(&kg[(size_t)(krb0 + keyo) * C3 + kslot], &Ks[0][krb0 * 64]);
        gload_lds16(&kg[(size_t)(krb1 + keyo) * C3 + kslot], &Ks[0][krb1 * 64]);
        bf16x8_t vv0 = *(const bf16x8_t*)&vg[(size_t)vr0 * C3 + vcb];
        bf16x8_t vv1 = *(const bf16x8_t*)&vg[(size_t)(vr0 + 32) * C3 + vcb];
        bf16x8_t qf0, qf1;
        {
            const __bf16* qrow = qg + (size_t)(qt0 + w * 16 + lr) * C3;
            qf0 = *(const bf16x8_t*)&qrow[lk];
            qf1 = *(const bf16x8_t*)&qrow[32 + lk];
        }

        f32x4_t o_acc[4];
#pragma unroll
        for (int i = 0; i < 4; ++i) o_acc[i] = (f32x4_t){0.f, 0.f, 0.f, 0.f};
        float m_r = -3.0e38f, l_r = 0.f;

        int cur = 0;
        for (int t = 0; t < nt; ++t) {
            __syncthreads();  // drains vmcnt: K(t) in Ks[cur], V(t) in regs; prev compute done

            // write V(t) into Vt (transposed, swizzled)
#pragma unroll
            for (int j = 0; j < 8; ++j) Vt[(vcb + j) * 72 + ks0] = vv0[j];
#pragma unroll
            for (int j = 0; j < 8; ++j) Vt[(vcb + j) * 72 + ks1] = vv1[j];

            __syncthreads();  // Vt(t) visible to all

            // issue next tile's loads (land during compute)
            if (t + 1 < nt) {
                const int kt1 = (t + 1) * 64;
                gload_lds16(&kg[(size_t)(kt1 + krb0 + keyo) * C3 + kslot], &Ks[cur ^ 1][krb0 * 64]);
                gload_lds16(&kg[(size_t)(kt1 + krb1 + keyo) * C3 + kslot], &Ks[cur ^ 1][krb1 * 64]);
                vv0 = *(const bf16x8_t*)&vg[(size_t)(kt1 + vr0) * C3 + vcb];
                vv1 = *(const bf16x8_t*)&vg[(size_t)(kt1 + vr0 + 32) * C3 + vcb];
            }

            // --- S^T = K Q^T : s[c][r] = S[q = qt0+w*16+lr][key = t*64 + c*16+lg*4+r]
            const __bf16* Kb = Ks[cur];
            f32x4_t s[4];
#pragma unroll
            for (int c = 0; c < 4; ++c) {
                const int key = c * 16 + lr;
                const int sw  = (key & 7) << 3;
                bf16x8_t kfa = *(const bf16x8_t*)&Kb[key * 64 + (lk ^ sw)];
                bf16x8_t kfb = *(const bf16x8_t*)&Kb[key * 64 + ((32 + lk) ^ sw)];
                s[c] = __builtin_amdgcn_mfma_f32_16x16x32_bf16(kfa, qf0, (f32x4_t){0.f, 0.f, 0.f, 0.f}, 0, 0, 0);
                s[c] = __builtin_amdgcn_mfma_f32_16x16x32_bf16(kfb, qf1, s[c], 0, 0, 0);
            }

            // --- causal mask (diagonal tile only) ---
            if (t == nt - 1) {
                const int ql = w * 16 + lr;
#pragma unroll
                for (int c = 0; c < 4; ++c)
#pragma unroll
                    for (int r = 0; r < 4; ++r)
                        if (c * 16 + lg * 4 + r > ql) s[c][r] = -1.0e30f;
            }

            // --- online softmax: all 16 values belong to query lr ---
            float pm = s[0][0];
#pragma unroll
            for (int c = 0; c < 4; ++c)
#pragma unroll
                for (int r = 0; r < 4; ++r) pm = fmaxf(pm, s[c][r]);
            pm = fmaxf(pm, __shfl_xor(pm, 16));
            pm = fmaxf(pm, __shfl_xor(pm, 32));

            const float mn    = fmaxf(m_r, pm);
            const float alpha = exp2f((m_r - mn) * CE);
            const float mce   = mn * CE;
            m_r = mn;

            float rs = 0.f;
#pragma unroll
            for (int c = 0; c < 4; ++c)
#pragma unroll
                for (int r = 0; r < 4; ++r) {
                    float pv = exp2f(fmaf(s[c][r], CE, -mce));
                    s[c][r] = pv;
                    rs += pv;
                }
            rs += __shfl_xor(rs, 16);
            rs += __shfl_xor(rs, 32);
            l_r = l_r * alpha + rs;
#pragma unroll
            for (int dt = 0; dt < 4; ++dt)
#pragma unroll
                for (int r = 0; r < 4; ++r) o_acc[dt][r] *= alpha;

            // --- P rows -> LDS: Pw[q=lr][key], 4 packed b64 writes ---
#pragma unroll
            for (int c = 0; c < 4; ++c) {
                bf16x4_t pk;
                pk[0] = (__bf16)s[c][0]; pk[1] = (__bf16)s[c][1];
                pk[2] = (__bf16)s[c][2]; pk[3] = (__bf16)s[c][3];
                *(bf16x4_t*)&Pw[lr * 72 + c * 16 + lg * 4] = pk;
            }

            // --- O^T += V^T P^T ---
            bf16x8_t pb0 = *(const bf16x8_t*)&Pw[lr * 72 + lk];
            bf16x8_t pb1 = *(const bf16x8_t*)&Pw[lr * 72 + 32 + lk];
#pragma unroll
            for (int dt = 0; dt < 4; ++dt) {
                const int d  = dt * 16 + lr;
                const int sw = ((d >> 3) & 7) << 3;
                bf16x8_t vb0 = *(const bf16x8_t*)&Vt[d * 72 + (lk ^ sw)];
                bf16x8_t vb1 = *(const bf16x8_t*)&Vt[d * 72 + ((32 + lk) ^ sw)];
                o_acc[dt] = __builtin_amdgcn_mfma_f32_16x16x32_bf16(vb0, pb0, o_acc[dt], 0, 0, 0);
                o_acc[dt] = __builtin_amdgcn_mfma_f32_16x16x32_bf16(vb1, pb1, o_acc[dt], 0, 0, 0);
            }

            cur ^= 1;
        }

        // --- epilogue: o[dt][r] = O[q = qt0+w*16+lr][d = dt*16 + lg*4 + r] ---
        const float inv = 1.0f / l_r;
        const int q = qt0 + w * 16 + lr;
#pragma unroll
        for (int dt = 0; dt < 4; ++dt) {
            bf16x4_t ov;
#pragma unroll
            for (int r = 0; r < 4; ++r) ov[r] = (__bf16)(o_acc[dt][r] * inv);
            *(bf16x4_t*)&y[(size_t)(b * T + q) * 1024 + h * HD + dt * 16 + lg * 4] = ov;
        }
    }
}

// ---------------- launch ----------------
extern "C" void kernel_launch(void* const* d_in, const int* in_sizes, int n_in,
                              void* d_out, int out_size, void* d_ws, size_t ws_size,
                              hipStream_t stream) {
    const float* x      = (const float*)d_in[0];
    const float* w_attn = (const float*)d_in[1];
    const float* w_proj = (const float*)d_in[2];
    float* out = (float*)d_out;

    char* ws = (char*)d_ws;
    __bf16* xb   = (__bf16*)(ws);                      // 8192*1024   = 16 MB
    __bf16* wab  = (__bf16*)(ws + 16777216);           // 3072*1024   = 6 MB
    __bf16* wpb  = (__bf16*)(ws + 23068672);           // 1024*1024   = 2 MB
    __bf16* qkvb = (__bf16*)(ws + 25165824);           // 8192*3072   = 48 MB
    __bf16* yb   = (__bf16*)(ws + 75497472);           // 8192*1024   = 16 MB

    f2bf_kernel<<<8192, 256, 0, stream>>>(x, xb, 8388608);
    f2bf_kernel<<<3072, 256, 0, stream>>>(w_attn, wab, 3145728);
    f2bf_kernel<<<1024, 256, 0, stream>>>(w_proj, wpb, 1048576);

    // qkv = x @ w_attn^T   [8192, 3072]
    gemm_bt<__bf16><<<dim3(24, 64), 256, 0, stream>>>(xb, wab, qkvb, 8192, 3072, 1024);

    // flash attention -> yb [8192, 1024]
    attn_kernel<<<1024, 256, 0, stream>>>(qkvb, yb);

    // out = yb @ w_proj^T  [8192, 1024] fp32
    gemm_bt<float><<<dim3(8, 64), 256, 0, stream>>>(yb, wpb, out, 8192, 1024, 1024);
}

// Round 4
// 190.887 us; speedup vs baseline: 2.2355x; 1.1561x over previous
//
#include <hip/hip_runtime.h>
#include <hip/hip_bf16.h>

typedef __bf16 bf16x8_t __attribute__((ext_vector_type(8)));
typedef __bf16 bf16x4_t __attribute__((ext_vector_type(4)));
typedef float f32x4_t __attribute__((ext_vector_type(4)));

__device__ __forceinline__ void gload_lds16(const void* g, void* l) {
    __builtin_amdgcn_global_load_lds((const __attribute__((address_space(1))) void*)g,
                                     (__attribute__((address_space(3))) void*)l, 16, 0, 0);
}

// ---------------- fp32 -> bf16 conversion ----------------
__global__ void f2bf_kernel(const float* __restrict__ in, __bf16* __restrict__ out, int n) {
    int i = (blockIdx.x * blockDim.x + threadIdx.x) * 4;
    if (i >= n) return;
    float4 v = *(const float4*)(in + i);
    bf16x4_t o;
    o[0] = (__bf16)v.x; o[1] = (__bf16)v.y; o[2] = (__bf16)v.z; o[3] = (__bf16)v.w;
    *(bf16x4_t*)(out + i) = o;
}

// ---------------- bf16 GEMM: C[M,N] = A[M,K] * Bt[N,K]^T ----------------
// 128x128 tile, BK=32, 4 waves; XCD-aware block swizzle (T1).
template <typename OutT>
__global__ __launch_bounds__(256) void gemm_bt(const __bf16* __restrict__ A,
                                               const __bf16* __restrict__ Bt,
                                               OutT* __restrict__ C,
                                               int M, int N, int K) {
    __shared__ __bf16 As[128 * 32];
    __shared__ __bf16 Bs[128 * 32];

    const int tid  = threadIdx.x;
    const int lane = tid & 63;
    const int wid  = tid >> 6;
    const int wm   = wid >> 1;
    const int wn   = wid & 1;

    // XCD swizzle: nwg % 8 == 0 for all our grids -> bijective
    const int nwg = gridDim.x * gridDim.y;
    int fl = blockIdx.y * gridDim.x + blockIdx.x;
    fl = (fl & 7) * (nwg >> 3) + (fl >> 3);
    const int m0 = (fl / gridDim.x) * 128;
    const int n0 = (fl % gridDim.x) * 128;

    const int lr = lane & 15;
    const int lk = (lane >> 4) * 8;
    const int cr = (lane >> 4) * 4;

    f32x4_t acc[4][4];
    for (int i = 0; i < 4; ++i)
        for (int j = 0; j < 4; ++j)
            acc[i][j] = (f32x4_t){0.f, 0.f, 0.f, 0.f};

    for (int k0 = 0; k0 < K; k0 += 32) {
        __syncthreads();
        for (int i = 0; i < 2; ++i) {
            int flat = i * 256 + tid;
            int row  = flat >> 2;
            int col  = (flat & 3) * 8;
            gload_lds16(&A[(size_t)(m0 + row) * K + k0 + col], &As[(size_t)(i * 256 + wid * 64) * 8]);
            gload_lds16(&Bt[(size_t)(n0 + row) * K + k0 + col], &Bs[(size_t)(i * 256 + wid * 64) * 8]);
        }
        __syncthreads();

        bf16x8_t af[4], bfr[4];
        for (int mf = 0; mf < 4; ++mf)
            af[mf] = *(const bf16x8_t*)&As[(wm * 64 + mf * 16 + lr) * 32 + lk];
        for (int nf = 0; nf < 4; ++nf)
            bfr[nf] = *(const bf16x8_t*)&Bs[(wn * 64 + nf * 16 + lr) * 32 + lk];
        for (int mf = 0; mf < 4; ++mf)
            for (int nf = 0; nf < 4; ++nf)
                acc[mf][nf] = __builtin_amdgcn_mfma_f32_16x16x32_bf16(af[mf], bfr[nf], acc[mf][nf], 0, 0, 0);
    }

    for (int mf = 0; mf < 4; ++mf)
        for (int nf = 0; nf < 4; ++nf)
            for (int r = 0; r < 4; ++r) {
                int row = m0 + wm * 64 + mf * 16 + cr + r;
                int col = n0 + wn * 64 + nf * 16 + lr;
                C[(size_t)row * N + col] = (OutT)acc[mf][nf][r];
            }
}

// ---------------- flash attention (causal), v4 ----------------
// QBLK=128 (8 waves x 16 q-rows), KVBLK=128. 512 blocks = b(4) x h(16) x pair(8);
// block does q-supertiles p and 15-p => 17 k-tiles total (balanced).
// XCD swizzle groups 8 same-(b,h) blocks per XCD for K/V L2 sharing.
// Reg-staged K+V (T14 issue-early/write-late); defer-max (T13).
__global__ __launch_bounds__(512, 4) void attn_kernel(const __bf16* __restrict__ qkv,
                                                      __bf16* __restrict__ y) {
    const int T = 2048, C3 = 3072;
    const int orig = blockIdx.x;
    const int bidx = ((orig & 7) << 6) + (orig >> 3);   // XCD swizzle (512 % 8 == 0)
    const int pair = bidx & 7;
    const int h    = (bidx >> 3) & 15;
    const int b    = bidx >> 7;

    __shared__ __bf16 Ks[128 * 64];      // [key][64 dims], content swizzled per row
    __shared__ __bf16 Vt[2][64 * 72];    // half: [d][key(0..63) swizzled]
    __shared__ __bf16 Ps[8 * 16 * 136];  // per-wave [q(16)][key(128)+pad]

    const int tid  = threadIdx.x;
    const int lane = tid & 63;
    const int w    = tid >> 6;
    const int lr   = lane & 15;
    const int lg   = lane >> 4;
    const int lk   = lg * 8;

    const __bf16* qg = qkv + (size_t)b * T * C3 + h * 64;
    const __bf16* kg = qg + 1024;
    const __bf16* vg = qg + 2048;

    const float CE    = 0.125f * 1.44269504f;   // scale * log2(e)
    const float DEFER = 44.0f;                  // 8 / CE in raw-score domain

    // staging map: thread covers rows r0 and 64+r0, dim chunk kcol..kcol+7
    const int r0    = tid >> 3;                 // 0..63
    const int kcol  = (tid & 7) * 8;
    const int kslot = ((tid & 7) ^ (r0 & 7)) << 3;   // K swizzled slot (same for r0, r0+64)
    const int vks   = r0 ^ ((tid & 7) << 3);         // V swizzled key slot (same both halves)

    __bf16* Pw = &Ps[w * 16 * 136];

    for (int pass = 0; pass < 2; ++pass) {
        const int qs  = pass ? 15 - pair : pair;
        const int qt0 = qs * 128;
        const int nt  = qs + 1;

        // Q fragments straight from global
        bf16x8_t qf0, qf1;
        {
            const __bf16* qrow = qg + (size_t)(qt0 + w * 16 + lr) * C3;
            qf0 = *(const bf16x8_t*)&qrow[lk];
            qf1 = *(const bf16x8_t*)&qrow[32 + lk];
        }

        // issue tile-0 K/V loads
        bf16x8_t ka = *(const bf16x8_t*)&kg[(size_t)r0 * C3 + kcol];
        bf16x8_t kb = *(const bf16x8_t*)&kg[(size_t)(64 + r0) * C3 + kcol];
        bf16x8_t va = *(const bf16x8_t*)&vg[(size_t)r0 * C3 + kcol];
        bf16x8_t vb = *(const bf16x8_t*)&vg[(size_t)(64 + r0) * C3 + kcol];

        f32x4_t o_acc[4];
#pragma unroll
        for (int i = 0; i < 4; ++i) o_acc[i] = (f32x4_t){0.f, 0.f, 0.f, 0.f};
        float m_r = -3.0e38f, l_r = 0.f;

        for (int t = 0; t < nt; ++t) {
            __syncthreads();  // prev tile reads done; staged regs landed (vmcnt drain)

            // write staged tile to LDS
            *(bf16x8_t*)&Ks[r0 * 64 + kslot] = ka;
            *(bf16x8_t*)&Ks[(64 + r0) * 64 + kslot] = kb;
#pragma unroll
            for (int j = 0; j < 8; ++j) Vt[0][(kcol + j) * 72 + vks] = va[j];
#pragma unroll
            for (int j = 0; j < 8; ++j) Vt[1][(kcol + j) * 72 + vks] = vb[j];

            __syncthreads();  // tile visible

            // issue next tile's loads (hide under compute)
            if (t + 1 < nt) {
                const size_t kb0 = (size_t)(t + 1) * 128;
                ka = *(const bf16x8_t*)&kg[(kb0 + r0) * C3 + kcol];
                kb = *(const bf16x8_t*)&kg[(kb0 + 64 + r0) * C3 + kcol];
                va = *(const bf16x8_t*)&vg[(kb0 + r0) * C3 + kcol];
                vb = *(const bf16x8_t*)&vg[(kb0 + 64 + r0) * C3 + kcol];
            }

            // --- S^T = K Q^T: s[c][r] = S[q=qt0+w*16+lr][key=t*128 + c*16+lg*4+r]
            f32x4_t s[8];
#pragma unroll
            for (int c = 0; c < 8; ++c) {
                const int key = c * 16 + lr;
                const int sw  = (key & 7) << 3;
                bf16x8_t kfa = *(const bf16x8_t*)&Ks[key * 64 + (lk ^ sw)];
                bf16x8_t kfb = *(const bf16x8_t*)&Ks[key * 64 + ((32 + lk) ^ sw)];
                s[c] = __builtin_amdgcn_mfma_f32_16x16x32_bf16(kfa, qf0, (f32x4_t){0.f, 0.f, 0.f, 0.f}, 0, 0, 0);
                s[c] = __builtin_amdgcn_mfma_f32_16x16x32_bf16(kfb, qf1, s[c], 0, 0, 0);
            }

            // --- causal mask (diagonal supertile only) ---
            if (t == nt - 1) {
                const int ql = w * 16 + lr;
#pragma unroll
                for (int c = 0; c < 8; ++c)
#pragma unroll
                    for (int r = 0; r < 4; ++r)
                        if (c * 16 + lg * 4 + r > ql) s[c][r] = -1.0e30f;
            }

            // --- online softmax with defer-max ---
            float pm = s[0][0];
#pragma unroll
            for (int c = 0; c < 8; ++c)
#pragma unroll
                for (int r = 0; r < 4; ++r) pm = fmaxf(pm, s[c][r]);

            if (!__all(pm <= m_r + DEFER)) {
                pm = fmaxf(pm, __shfl_xor(pm, 16));
                pm = fmaxf(pm, __shfl_xor(pm, 32));
                const float mn    = fmaxf(m_r, pm);
                const float alpha = exp2f((m_r - mn) * CE);
                l_r *= alpha;
#pragma unroll
                for (int dt = 0; dt < 4; ++dt)
#pragma unroll
                    for (int r = 0; r < 4; ++r) o_acc[dt][r] *= alpha;
                m_r = mn;
            }
            const float mce = m_r * CE;

            float rs = 0.f;
#pragma unroll
            for (int c = 0; c < 8; ++c) {
                bf16x4_t pk;
#pragma unroll
                for (int r = 0; r < 4; ++r) {
                    float pv = exp2f(fmaf(s[c][r], CE, -mce));
                    rs += pv;
                    pk[r] = (__bf16)pv;
                }
                *(bf16x4_t*)&Pw[lr * 136 + c * 16 + lg * 4] = pk;
            }
            rs += __shfl_xor(rs, 16);
            rs += __shfl_xor(rs, 32);
            l_r += rs;

            // --- O^T += V^T P^T ---
#pragma unroll
            for (int hf = 0; hf < 2; ++hf) {
                bf16x8_t pb0 = *(const bf16x8_t*)&Pw[lr * 136 + hf * 64 + lk];
                bf16x8_t pb1 = *(const bf16x8_t*)&Pw[lr * 136 + hf * 64 + 32 + lk];
#pragma unroll
                for (int dt = 0; dt < 4; ++dt) {
                    const int d   = dt * 16 + lr;
                    const int sw2 = ((d >> 3) & 7) << 3;
                    bf16x8_t vb0 = *(const bf16x8_t*)&Vt[hf][d * 72 + (lk ^ sw2)];
                    bf16x8_t vb1 = *(const bf16x8_t*)&Vt[hf][d * 72 + ((32 + lk) ^ sw2)];
                    o_acc[dt] = __builtin_amdgcn_mfma_f32_16x16x32_bf16(vb0, pb0, o_acc[dt], 0, 0, 0);
                    o_acc[dt] = __builtin_amdgcn_mfma_f32_16x16x32_bf16(vb1, pb1, o_acc[dt], 0, 0, 0);
                }
            }
        }

        // --- epilogue ---
        const float inv = 1.0f / l_r;
        const int q = qt0 + w * 16 + lr;
#pragma unroll
        for (int dt = 0; dt < 4; ++dt) {
            bf16x4_t ov;
#pragma unroll
            for (int r = 0; r < 4; ++r) ov[r] = (__bf16)(o_acc[dt][r] * inv);
            *(bf16x4_t*)&y[(size_t)(b * T + q) * 1024 + h * 64 + dt * 16 + lg * 4] = ov;
        }
    }
}

// ---------------- launch ----------------
extern "C" void kernel_launch(void* const* d_in, const int* in_sizes, int n_in,
                              void* d_out, int out_size, void* d_ws, size_t ws_size,
                              hipStream_t stream) {
    const float* x      = (const float*)d_in[0];
    const float* w_attn = (const float*)d_in[1];
    const float* w_proj = (const float*)d_in[2];
    float* out = (float*)d_out;

    char* ws = (char*)d_ws;
    __bf16* xb   = (__bf16*)(ws);                      // 8192*1024   = 16 MB
    __bf16* wab  = (__bf16*)(ws + 16777216);           // 3072*1024   = 6 MB
    __bf16* wpb  = (__bf16*)(ws + 23068672);           // 1024*1024   = 2 MB
    __bf16* qkvb = (__bf16*)(ws + 25165824);           // 8192*3072   = 48 MB
    __bf16* yb   = (__bf16*)(ws + 75497472);           // 8192*1024   = 16 MB

    f2bf_kernel<<<8192, 256, 0, stream>>>(x, xb, 8388608);
    f2bf_kernel<<<3072, 256, 0, stream>>>(w_attn, wab, 3145728);
    f2bf_kernel<<<1024, 256, 0, stream>>>(w_proj, wpb, 1048576);

    // qkv = x @ w_attn^T   [8192, 3072]
    gemm_bt<__bf16><<<dim3(24, 64), 256, 0, stream>>>(xb, wab, qkvb, 8192, 3072, 1024);

    // flash attention -> yb [8192, 1024]
    attn_kernel<<<512, 512, 0, stream>>>(qkvb, yb);

    // out = yb @ w_proj^T  [8192, 1024] fp32
    gemm_bt<float><<<dim3(8, 64), 256, 0, stream>>>(yb, wpb, out, 8192, 1024, 1024);
}

// Round 5
// 188.646 us; speedup vs baseline: 2.2621x; 1.0119x over previous
//
#include <hip/hip_runtime.h>
#include <hip/hip_bf16.h>

typedef __bf16 bf16x8_t __attribute__((ext_vector_type(8)));
typedef __bf16 bf16x4_t __attribute__((ext_vector_type(4)));
typedef float f32x4_t __attribute__((ext_vector_type(4)));

__device__ __forceinline__ void gload_lds16(const void* g, void* l) {
    __builtin_amdgcn_global_load_lds((const __attribute__((address_space(1))) void*)g,
                                     (__attribute__((address_space(3))) void*)l, 16, 0, 0);
}

// ---------------- fp32 -> bf16 conversion ----------------
__global__ void f2bf_kernel(const float* __restrict__ in, __bf16* __restrict__ out, int n) {
    int i = (blockIdx.x * blockDim.x + threadIdx.x) * 4;
    if (i >= n) return;
    float4 v = *(const float4*)(in + i);
    bf16x4_t o;
    o[0] = (__bf16)v.x; o[1] = (__bf16)v.y; o[2] = (__bf16)v.z; o[3] = (__bf16)v.w;
    *(bf16x4_t*)(out + i) = o;
}

// ---------------- GEMM1: 8-phase pipelined, BM=128 BN=256 BK=64 ----------------
// C[M,N] = A[M,K] * Bt[N,K]^T, bf16 out. 8 waves (2M x 4N), per-wave 64x64.
// Double-buffered LDS (96KB), global_load_lds staging with chunk-XOR swizzle
// (slot = chunk ^ (row&7), pre-swizzled global source), counted vmcnt (never 0
// in steady state), raw s_barrier, setprio around MFMA clusters.
__global__ __launch_bounds__(512, 2) void gemm1_8ph(const __bf16* __restrict__ A,
                                                    const __bf16* __restrict__ Bt,
                                                    __bf16* __restrict__ C,
                                                    int M, int N, int K) {
    __shared__ __bf16 AsB[2][16 * 512];   // 128 rows x 64 cols per buf
    __shared__ __bf16 BsB[2][32 * 512];   // 256 rows x 64 cols per buf

    const int tid  = threadIdx.x;
    const int lane = tid & 63;
    const int wid  = tid >> 6;
    const int wm   = wid >> 2;      // 0..1 (M half)
    const int wn   = wid & 3;       // 0..3 (N quarter)

    // XCD swizzle (grid 768 % 8 == 0 -> bijective); n-major within chunk
    const int nwg   = gridDim.x;
    const int ntile = N >> 8;
    int fl = blockIdx.x;
    fl = (fl & 7) * (nwg >> 3) + (fl >> 3);
    const int m0 = (fl / ntile) * 128;
    const int n0 = (fl % ntile) * 256;

    const int lr = lane & 15;
    const int lg = lane >> 4;
    const int cr = lg * 4;
    // staging: lane covers row srow within an 8-row segment, source chunk pre-swizzled
    const int srow = lane >> 3;
    const int gcol = (((lane & 7) ^ srow) << 3);

    f32x4_t acc[4][4];
#pragma unroll
    for (int i = 0; i < 4; ++i)
#pragma unroll
        for (int j = 0; j < 4; ++j)
            acc[i][j] = (f32x4_t){0.f, 0.f, 0.f, 0.f};

    const int NT = K >> 6;   // 64-wide K-tiles

    auto stage = [&](int kt, int buf) {
        const __bf16* Ab = A + (size_t)m0 * K + kt * 64;
        const __bf16* Bb = Bt + (size_t)n0 * K + kt * 64;
        __bf16* Al = &AsB[buf][0];
        __bf16* Bl = &BsB[buf][0];
#pragma unroll
        for (int j = 0; j < 6; ++j) {
            int seg = wid * 6 + j;           // 0..47: 16 A segments, 32 B segments
            if (seg < 16) {
                gload_lds16(Ab + (size_t)(seg * 8 + srow) * K + gcol, Al + seg * 512);
            } else {
                int s2 = seg - 16;
                gload_lds16(Bb + (size_t)(s2 * 8 + srow) * K + gcol, Bl + s2 * 512);
            }
        }
    };

    stage(0, 0);

    for (int kt = 0; kt < NT; ++kt) {
        const int cur = kt & 1;
        const bool pf = (kt + 1 < NT);
        if (pf) stage(kt + 1, cur ^ 1);

        if (pf) asm volatile("s_waitcnt vmcnt(6)" ::: "memory");
        else    asm volatile("s_waitcnt vmcnt(0)" ::: "memory");
        __builtin_amdgcn_sched_barrier(0);
        __builtin_amdgcn_s_barrier();
        __builtin_amdgcn_sched_barrier(0);

        const __bf16* Al = &AsB[cur][0];
        const __bf16* Bl = &BsB[cur][0];

        // A fragments for the whole K-tile (live across both phases)
        bf16x8_t af[4][2];
#pragma unroll
        for (int mf = 0; mf < 4; ++mf)
#pragma unroll
            for (int kk = 0; kk < 2; ++kk) {
                const int row = wm * 64 + mf * 16 + lr;
                const int g   = kk * 4 + lg;
                af[mf][kk] = *(const bf16x8_t*)&Al[row * 64 + ((g ^ (row & 7)) << 3)];
            }

#pragma unroll
        for (int p = 0; p < 2; ++p) {
            bf16x8_t bfr[2][2];
#pragma unroll
            for (int nfp = 0; nfp < 2; ++nfp)
#pragma unroll
                for (int kk = 0; kk < 2; ++kk) {
                    const int row = wn * 64 + (p * 2 + nfp) * 16 + lr;
                    const int g   = kk * 4 + lg;
                    bfr[nfp][kk] = *(const bf16x8_t*)&Bl[row * 64 + ((g ^ (row & 7)) << 3)];
                }
            __builtin_amdgcn_s_setprio(1);
#pragma unroll
            for (int mf = 0; mf < 4; ++mf)
#pragma unroll
                for (int nfp = 0; nfp < 2; ++nfp) {
                    const int nf = p * 2 + nfp;
                    acc[mf][nf] = __builtin_amdgcn_mfma_f32_16x16x32_bf16(af[mf][0], bfr[nfp][0], acc[mf][nf], 0, 0, 0);
                    acc[mf][nf] = __builtin_amdgcn_mfma_f32_16x16x32_bf16(af[mf][1], bfr[nfp][1], acc[mf][nf], 0, 0, 0);
                }
            __builtin_amdgcn_s_setprio(0);
            __builtin_amdgcn_s_barrier();
        }
        __builtin_amdgcn_sched_barrier(0);
    }

#pragma unroll
    for (int mf = 0; mf < 4; ++mf)
#pragma unroll
        for (int nf = 0; nf < 4; ++nf)
#pragma unroll
            for (int r = 0; r < 4; ++r) {
                int row = m0 + wm * 64 + mf * 16 + cr + r;
                int col = n0 + wn * 64 + nf * 16 + lr;
                C[(size_t)row * N + col] = (__bf16)acc[mf][nf][r];
            }
}

// ---------------- bf16 GEMM (128x128, used for proj): C = A * Bt^T ----------------
template <typename OutT>
__global__ __launch_bounds__(256) void gemm_bt(const __bf16* __restrict__ A,
                                               const __bf16* __restrict__ Bt,
                                               OutT* __restrict__ C,
                                               int M, int N, int K) {
    __shared__ __bf16 As[128 * 32];
    __shared__ __bf16 Bs[128 * 32];

    const int tid  = threadIdx.x;
    const int lane = tid & 63;
    const int wid  = tid >> 6;
    const int wm   = wid >> 1;
    const int wn   = wid & 1;

    const int nwg = gridDim.x * gridDim.y;
    int fl = blockIdx.y * gridDim.x + blockIdx.x;
    fl = (fl & 7) * (nwg >> 3) + (fl >> 3);
    const int m0 = (fl / gridDim.x) * 128;
    const int n0 = (fl % gridDim.x) * 128;

    const int lr = lane & 15;
    const int lk = (lane >> 4) * 8;
    const int cr = (lane >> 4) * 4;

    f32x4_t acc[4][4];
    for (int i = 0; i < 4; ++i)
        for (int j = 0; j < 4; ++j)
            acc[i][j] = (f32x4_t){0.f, 0.f, 0.f, 0.f};

    for (int k0 = 0; k0 < K; k0 += 32) {
        __syncthreads();
        for (int i = 0; i < 2; ++i) {
            int flat = i * 256 + tid;
            int row  = flat >> 2;
            int col  = (flat & 3) * 8;
            gload_lds16(&A[(size_t)(m0 + row) * K + k0 + col], &As[(size_t)(i * 256 + wid * 64) * 8]);
            gload_lds16(&Bt[(size_t)(n0 + row) * K + k0 + col], &Bs[(size_t)(i * 256 + wid * 64) * 8]);
        }
        __syncthreads();

        bf16x8_t af[4], bfr[4];
        for (int mf = 0; mf < 4; ++mf)
            af[mf] = *(const bf16x8_t*)&As[(wm * 64 + mf * 16 + lr) * 32 + lk];
        for (int nf = 0; nf < 4; ++nf)
            bfr[nf] = *(const bf16x8_t*)&Bs[(wn * 64 + nf * 16 + lr) * 32 + lk];
        for (int mf = 0; mf < 4; ++mf)
            for (int nf = 0; nf < 4; ++nf)
                acc[mf][nf] = __builtin_amdgcn_mfma_f32_16x16x32_bf16(af[mf], bfr[nf], acc[mf][nf], 0, 0, 0);
    }

    for (int mf = 0; mf < 4; ++mf)
        for (int nf = 0; nf < 4; ++nf)
            for (int r = 0; r < 4; ++r) {
                int row = m0 + wm * 64 + mf * 16 + cr + r;
                int col = n0 + wn * 64 + nf * 16 + lr;
                C[(size_t)row * N + col] = (OutT)acc[mf][nf][r];
            }
}

// ---------------- flash attention (causal), v4 ----------------
__global__ __launch_bounds__(512, 4) void attn_kernel(const __bf16* __restrict__ qkv,
                                                      __bf16* __restrict__ y) {
    const int T = 2048, C3 = 3072;
    const int orig = blockIdx.x;
    const int bidx = ((orig & 7) << 6) + (orig >> 3);   // XCD swizzle (512 % 8 == 0)
    const int pair = bidx & 7;
    const int h    = (bidx >> 3) & 15;
    const int b    = bidx >> 7;

    __shared__ __bf16 Ks[128 * 64];
    __shared__ __bf16 Vt[2][64 * 72];
    __shared__ __bf16 Ps[8 * 16 * 136];

    const int tid  = threadIdx.x;
    const int lane = tid & 63;
    const int w    = tid >> 6;
    const int lr   = lane & 15;
    const int lg   = lane >> 4;
    const int lk   = lg * 8;

    const __bf16* qg = qkv + (size_t)b * T * C3 + h * 64;
    const __bf16* kg = qg + 1024;
    const __bf16* vg = qg + 2048;

    const float CE    = 0.125f * 1.44269504f;
    const float DEFER = 44.0f;

    const int r0    = tid >> 3;
    const int kcol  = (tid & 7) * 8;
    const int kslot = ((tid & 7) ^ (r0 & 7)) << 3;
    const int vks   = r0 ^ ((tid & 7) << 3);

    __bf16* Pw = &Ps[w * 16 * 136];

    for (int pass = 0; pass < 2; ++pass) {
        const int qs  = pass ? 15 - pair : pair;
        const int qt0 = qs * 128;
        const int nt  = qs + 1;

        bf16x8_t qf0, qf1;
        {
            const __bf16* qrow = qg + (size_t)(qt0 + w * 16 + lr) * C3;
            qf0 = *(const bf16x8_t*)&qrow[lk];
            qf1 = *(const bf16x8_t*)&qrow[32 + lk];
        }

        bf16x8_t ka = *(const bf16x8_t*)&kg[(size_t)r0 * C3 + kcol];
        bf16x8_t kb = *(const bf16x8_t*)&kg[(size_t)(64 + r0) * C3 + kcol];
        bf16x8_t va = *(const bf16x8_t*)&vg[(size_t)r0 * C3 + kcol];
        bf16x8_t vb = *(const bf16x8_t*)&vg[(size_t)(64 + r0) * C3 + kcol];

        f32x4_t o_acc[4];
#pragma unroll
        for (int i = 0; i < 4; ++i) o_acc[i] = (f32x4_t){0.f, 0.f, 0.f, 0.f};
        float m_r = -3.0e38f, l_r = 0.f;

        for (int t = 0; t < nt; ++t) {
            __syncthreads();

            *(bf16x8_t*)&Ks[r0 * 64 + kslot] = ka;
            *(bf16x8_t*)&Ks[(64 + r0) * 64 + kslot] = kb;
#pragma unroll
            for (int j = 0; j < 8; ++j) Vt[0][(kcol + j) * 72 + vks] = va[j];
#pragma unroll
            for (int j = 0; j < 8; ++j) Vt[1][(kcol + j) * 72 + vks] = vb[j];

            __syncthreads();

            if (t + 1 < nt) {
                const size_t kb0 = (size_t)(t + 1) * 128;
                ka = *(const bf16x8_t*)&kg[(kb0 + r0) * C3 + kcol];
                kb = *(const bf16x8_t*)&kg[(kb0 + 64 + r0) * C3 + kcol];
                va = *(const bf16x8_t*)&vg[(kb0 + r0) * C3 + kcol];
                vb = *(const bf16x8_t*)&vg[(kb0 + 64 + r0) * C3 + kcol];
            }

            f32x4_t s[8];
#pragma unroll
            for (int c = 0; c < 8; ++c) {
                const int key = c * 16 + lr;
                const int sw  = (key & 7) << 3;
                bf16x8_t kfa = *(const bf16x8_t*)&Ks[key * 64 + (lk ^ sw)];
                bf16x8_t kfb = *(const bf16x8_t*)&Ks[key * 64 + ((32 + lk) ^ sw)];
                s[c] = __builtin_amdgcn_mfma_f32_16x16x32_bf16(kfa, qf0, (f32x4_t){0.f, 0.f, 0.f, 0.f}, 0, 0, 0);
                s[c] = __builtin_amdgcn_mfma_f32_16x16x32_bf16(kfb, qf1, s[c], 0, 0, 0);
            }

            if (t == nt - 1) {
                const int ql = w * 16 + lr;
#pragma unroll
                for (int c = 0; c < 8; ++c)
#pragma unroll
                    for (int r = 0; r < 4; ++r)
                        if (c * 16 + lg * 4 + r > ql) s[c][r] = -1.0e30f;
            }

            float pm = s[0][0];
#pragma unroll
            for (int c = 0; c < 8; ++c)
#pragma unroll
                for (int r = 0; r < 4; ++r) pm = fmaxf(pm, s[c][r]);

            if (!__all(pm <= m_r + DEFER)) {
                pm = fmaxf(pm, __shfl_xor(pm, 16));
                pm = fmaxf(pm, __shfl_xor(pm, 32));
                const float mn    = fmaxf(m_r, pm);
                const float alpha = exp2f((m_r - mn) * CE);
                l_r *= alpha;
#pragma unroll
                for (int dt = 0; dt < 4; ++dt)
#pragma unroll
                    for (int r = 0; r < 4; ++r) o_acc[dt][r] *= alpha;
                m_r = mn;
            }
            const float mce = m_r * CE;

            float rs = 0.f;
#pragma unroll
            for (int c = 0; c < 8; ++c) {
                bf16x4_t pk;
#pragma unroll
                for (int r = 0; r < 4; ++r) {
                    float pv = exp2f(fmaf(s[c][r], CE, -mce));
                    rs += pv;
                    pk[r] = (__bf16)pv;
                }
                *(bf16x4_t*)&Pw[lr * 136 + c * 16 + lg * 4] = pk;
            }
            rs += __shfl_xor(rs, 16);
            rs += __shfl_xor(rs, 32);
            l_r += rs;

#pragma unroll
            for (int hf = 0; hf < 2; ++hf) {
                bf16x8_t pb0 = *(const bf16x8_t*)&Pw[lr * 136 + hf * 64 + lk];
                bf16x8_t pb1 = *(const bf16x8_t*)&Pw[lr * 136 + hf * 64 + 32 + lk];
#pragma unroll
                for (int dt = 0; dt < 4; ++dt) {
                    const int d   = dt * 16 + lr;
                    const int sw2 = ((d >> 3) & 7) << 3;
                    bf16x8_t vb0 = *(const bf16x8_t*)&Vt[hf][d * 72 + (lk ^ sw2)];
                    bf16x8_t vb1 = *(const bf16x8_t*)&Vt[hf][d * 72 + ((32 + lk) ^ sw2)];
                    o_acc[dt] = __builtin_amdgcn_mfma_f32_16x16x32_bf16(vb0, pb0, o_acc[dt], 0, 0, 0);
                    o_acc[dt] = __builtin_amdgcn_mfma_f32_16x16x32_bf16(vb1, pb1, o_acc[dt], 0, 0, 0);
                }
            }
        }

        const float inv = 1.0f / l_r;
        const int q = qt0 + w * 16 + lr;
#pragma unroll
        for (int dt = 0; dt < 4; ++dt) {
            bf16x4_t ov;
#pragma unroll
            for (int r = 0; r < 4; ++r) ov[r] = (__bf16)(o_acc[dt][r] * inv);
            *(bf16x4_t*)&y[(size_t)(b * T + q) * 1024 + h * 64 + dt * 16 + lg * 4] = ov;
        }
    }
}

// ---------------- launch ----------------
extern "C" void kernel_launch(void* const* d_in, const int* in_sizes, int n_in,
                              void* d_out, int out_size, void* d_ws, size_t ws_size,
                              hipStream_t stream) {
    const float* x      = (const float*)d_in[0];
    const float* w_attn = (const float*)d_in[1];
    const float* w_proj = (const float*)d_in[2];
    float* out = (float*)d_out;

    char* ws = (char*)d_ws;
    __bf16* xb   = (__bf16*)(ws);                      // 8192*1024   = 16 MB
    __bf16* wab  = (__bf16*)(ws + 16777216);           // 3072*1024   = 6 MB
    __bf16* wpb  = (__bf16*)(ws + 23068672);           // 1024*1024   = 2 MB
    __bf16* qkvb = (__bf16*)(ws + 25165824);           // 8192*3072   = 48 MB
    __bf16* yb   = (__bf16*)(ws + 75497472);           // 8192*1024   = 16 MB

    f2bf_kernel<<<8192, 256, 0, stream>>>(x, xb, 8388608);
    f2bf_kernel<<<3072, 256, 0, stream>>>(w_attn, wab, 3145728);
    f2bf_kernel<<<1024, 256, 0, stream>>>(w_proj, wpb, 1048576);

    // qkv = x @ w_attn^T   [8192, 3072]  (8-phase pipelined GEMM)
    gemm1_8ph<<<768, 512, 0, stream>>>(xb, wab, qkvb, 8192, 3072, 1024);

    // flash attention -> yb [8192, 1024]
    attn_kernel<<<512, 512, 0, stream>>>(qkvb, yb);

    // out = yb @ w_proj^T  [8192, 1024] fp32
    gemm_bt<float><<<dim3(8, 64), 256, 0, stream>>>(yb, wpb, out, 8192, 1024, 1024);
}